// Round 1
// baseline (729.455 us; speedup 1.0000x reference)
//
#include <hip/hip_runtime.h>
#include <math.h>

// ---------------------------------------------------------------------------
// z = A[M,K] @ B[64,K]^T  -> C[M,64]   (fp32 vector GEMM, 64x64 tile, KB=32)
// ---------------------------------------------------------------------------
__global__ __launch_bounds__(256) void gemm_nt(const float* __restrict__ A,
                                               const float* __restrict__ B,
                                               float* __restrict__ C,
                                               int M, int K) {
  __shared__ float As[32][68];  // [k][m], padded
  __shared__ float Bs[32][68];  // [k][n], padded
  const int t = threadIdx.x;
  const int rBase = blockIdx.x * 64;
  const int tx = t & 15, ty = t >> 4;
  const int n0 = tx * 4, m0 = ty * 4;
  float acc[4][4] = {};

  for (int kb = 0; kb < K; kb += 32) {
    #pragma unroll
    for (int q = 0; q < 2; ++q) {
      int f = t * 2 + q;          // 0..511
      int row = f >> 3;           // 0..63
      int kq = f & 7;             // 0..7 (float4 chunk)
      int gr = rBase + row;
      float4 av = make_float4(0.f, 0.f, 0.f, 0.f);
      if (gr < M) av = *(const float4*)(A + (size_t)gr * K + kb + kq * 4);
      As[kq * 4 + 0][row] = av.x;
      As[kq * 4 + 1][row] = av.y;
      As[kq * 4 + 2][row] = av.z;
      As[kq * 4 + 3][row] = av.w;
      float4 bv = *(const float4*)(B + (size_t)row * K + kb + kq * 4);
      Bs[kq * 4 + 0][row] = bv.x;
      Bs[kq * 4 + 1][row] = bv.y;
      Bs[kq * 4 + 2][row] = bv.z;
      Bs[kq * 4 + 3][row] = bv.w;
    }
    __syncthreads();
    #pragma unroll
    for (int k = 0; k < 32; ++k) {
      float4 a = *(const float4*)&As[k][m0];
      float4 b = *(const float4*)&Bs[k][n0];
      acc[0][0] += a.x * b.x; acc[0][1] += a.x * b.y; acc[0][2] += a.x * b.z; acc[0][3] += a.x * b.w;
      acc[1][0] += a.y * b.x; acc[1][1] += a.y * b.y; acc[1][2] += a.y * b.z; acc[1][3] += a.y * b.w;
      acc[2][0] += a.z * b.x; acc[2][1] += a.z * b.y; acc[2][2] += a.z * b.z; acc[2][3] += a.z * b.w;
      acc[3][0] += a.w * b.x; acc[3][1] += a.w * b.y; acc[3][2] += a.w * b.z; acc[3][3] += a.w * b.w;
    }
    __syncthreads();
  }
  #pragma unroll
  for (int ii = 0; ii < 4; ++ii) {
    int gr = rBase + m0 + ii;
    if (gr < M) {
      float4 o = make_float4(acc[ii][0], acc[ii][1], acc[ii][2], acc[ii][3]);
      *(float4*)(C + (size_t)gr * 64 + n0) = o;
    }
  }
}

// ---------------------------------------------------------------------------
// CSR build: count -> scan -> scatter
// ---------------------------------------------------------------------------
__global__ void count_deg(const int* __restrict__ dst, int* __restrict__ cnt, int E) {
  int i = blockIdx.x * blockDim.x + threadIdx.x;
  if (i < E) atomicAdd(&cnt[dst[i]], 1);
}

// single block, 1024 threads; reads cnt (degrees), writes exclusive prefix to
// offsets[] AND back into cnt[] (becomes the scatter cursor). offsets[n]=E.
__global__ __launch_bounds__(1024) void scan_deg(int* __restrict__ cnt,
                                                 int* __restrict__ offsets, int n) {
  __shared__ int waveSums[16];
  const int t = threadIdx.x;
  const int lane = t & 63, wave = t >> 6;
  const int PER = 8;
  const int CHUNK = 1024 * PER;
  int running = 0;
  for (int c0 = 0; c0 < n; c0 += CHUNK) {
    int idx0 = c0 + t * PER;
    int v[PER];
    int s = 0;
    #pragma unroll
    for (int j = 0; j < PER; ++j) {
      int i = idx0 + j;
      int x = (i < n) ? cnt[i] : 0;
      v[j] = s;  // exclusive within thread
      s += x;
    }
    // wave inclusive scan of per-thread totals
    int inc = s;
    #pragma unroll
    for (int d = 1; d < 64; d <<= 1) {
      int o = __shfl_up(inc, d, 64);
      if (lane >= d) inc += o;
    }
    int excl = inc - s;
    if (lane == 63) waveSums[wave] = inc;
    __syncthreads();
    int waveBase = 0, total = 0;
    #pragma unroll
    for (int w = 0; w < 16; ++w) {
      int ws_v = waveSums[w];
      if (w < wave) waveBase += ws_v;
      total += ws_v;
    }
    int base = running + waveBase + excl;
    #pragma unroll
    for (int j = 0; j < PER; ++j) {
      int i = idx0 + j;
      if (i < n) {
        offsets[i] = base + v[j];
        cnt[i] = base + v[j];
      }
    }
    running += total;
    __syncthreads();
  }
  if (t == 0) offsets[n] = running;
}

__global__ void scatter_edges(const int* __restrict__ dst, const int* __restrict__ src,
                              int* __restrict__ cursor, int* __restrict__ edgeSrc, int E) {
  int i = blockIdx.x * blockDim.x + threadIdx.x;
  if (i < E) {
    int pos = atomicAdd(&cursor[dst[i]], 1);
    edgeSrc[pos] = src[i];
  }
}

// ---------------------------------------------------------------------------
// One wave per dst node: online-softmax weighted aggregation.
// lane = output dim (OUT_DIM == 64 == wavefront size).
// ---------------------------------------------------------------------------
__global__ __launch_bounds__(256) void aggregate(const float* __restrict__ z,
                                                 const float* __restrict__ df,
                                                 const int* __restrict__ offsets,
                                                 const int* __restrict__ edgeSrc,
                                                 float* __restrict__ out, int N) {
  int gwave = (blockIdx.x * blockDim.x + threadIdx.x) >> 6;
  int lane = threadIdx.x & 63;
  if (gwave >= N) return;
  const int d = gwave;
  const float dfv = df[(size_t)d * 64 + lane];
  const int beg = offsets[d];
  const int end = offsets[d + 1];

  float m = -INFINITY, l = 0.f, acc = 0.f;
  for (int j = beg; j < end; ++j) {
    int s = edgeSrc[j];  // uniform across wave (same address -> broadcast)
    float zv = z[(size_t)s * 64 + lane];
    float p = zv * dfv;
    #pragma unroll
    for (int o = 32; o > 0; o >>= 1) p += __shfl_xor(p, o, 64);
    // p now holds e = dot(z[src], df[dst]) in all lanes
    float nm = fmaxf(m, p);
    float alpha = __expf(m - nm);  // first iter: exp(-inf) = 0
    float w = __expf(p - nm);
    l = l * alpha + w;
    acc = acc * alpha + w * zv;
    m = nm;
  }
  out[(size_t)d * 64 + lane] = (l > 0.f) ? (acc / l) : 0.f;
}

// ---------------------------------------------------------------------------
extern "C" void kernel_launch(void* const* d_in, const int* in_sizes, int n_in,
                              void* d_out, int out_size, void* d_ws, size_t ws_size,
                              hipStream_t stream) {
  const float* h     = (const float*)d_in[0];  // [N,256]
  const float* feat  = (const float*)d_in[1];  // [N,64]
  const float* W_fc  = (const float*)d_in[2];  // [64,256]
  const float* W_dst = (const float*)d_in[3];  // [64,64]
  const int*   src   = (const int*)d_in[4];    // [E]
  const int*   dst   = (const int*)d_in[5];    // [E]
  float* out = (float*)d_out;

  const int N = in_sizes[1] / 64;   // 100000
  const int E = in_sizes[4];        // 1600000
  const int IN_DIM = in_sizes[0] / N;   // 256
  const int FEAT_DIM = 64;

  // workspace layout
  char* ws = (char*)d_ws;
  float* z  = (float*)ws;                       // N*64 f32
  float* df = z + (size_t)N * 64;               // N*64 f32
  int* offsets = (int*)(df + (size_t)N * 64);   // N+1
  int* cursor  = offsets + (N + 1);             // N   (deg -> prefix -> cursor)
  int* edgeSrc = cursor + N;                    // E

  hipMemsetAsync(cursor, 0, sizeof(int) * (size_t)N, stream);

  gemm_nt<<<(N + 63) / 64, 256, 0, stream>>>(h, W_fc, z, N, IN_DIM);
  gemm_nt<<<(N + 63) / 64, 256, 0, stream>>>(feat, W_dst, df, N, FEAT_DIM);

  int egrid = (E + 255) / 256;
  count_deg<<<egrid, 256, 0, stream>>>(dst, cursor, E);
  scan_deg<<<1, 1024, 0, stream>>>(cursor, offsets, N);
  scatter_edges<<<egrid, 256, 0, stream>>>(dst, src, cursor, edgeSrc, E);

  aggregate<<<(N + 3) / 4, 256, 0, stream>>>(z, df, offsets, edgeSrc, out, N);
}